// Round 1
// baseline (887.986 us; speedup 1.0000x reference)
//
#include <hip/hip_runtime.h>
#include <math.h>

// Problem constants (from reference setup_inputs)
constexpr int N    = 50000;   // nodes
constexpr int E    = 800000;  // edges
constexpr int CIN  = 100;     // input channels
constexpr int CH   = 128;     // hidden channels
constexpr int COUT = 47;      // output channels
constexpr int NOUT = 25000;   // original_size (rows emitted)

// ---------------------------------------------------------------------------
// Stage 1: degree = segment_sum(ones, dst)
__global__ void deg_kernel(const int* __restrict__ dst, float* __restrict__ deg) {
    int i = blockIdx.x * blockDim.x + threadIdx.x;
    if (i < E) atomicAdd(&deg[dst[i]], 1.0f);
}

// ---------------------------------------------------------------------------
// Stage 2: agg1[dst] += x[src]   (edge x feature grid, 100 feats/edge)
__global__ void scatter1(const float* __restrict__ x,
                         const int* __restrict__ src,
                         const int* __restrict__ dst,
                         float* __restrict__ agg1) {
    int idx = blockIdx.x * blockDim.x + threadIdx.x;   // < E*CIN = 80M < 2^31
    if (idx >= E * CIN) return;
    int e = idx / CIN;
    int f = idx - e * CIN;
    int d = dst[e];
    int s = src[e];
    atomicAdd(&agg1[d * CIN + f], x[s * CIN + f]);
}

// ---------------------------------------------------------------------------
// Stage 3: h[n] = (agg1[n]/max(deg,1)) @ w1_l + x[n] @ w1_r + b1_l
// One block of 128 threads per node; row staged in LDS; thread c computes
// hidden channel c. Weight reads are coalesced across threads (c contiguous).
__global__ __launch_bounds__(128) void layer1(
        const float* __restrict__ x, const float* __restrict__ agg1,
        const float* __restrict__ deg,
        const float* __restrict__ w1l, const float* __restrict__ b1l,
        const float* __restrict__ w1r,
        float* __restrict__ h) {
    int n = blockIdx.x;
    int c = threadIdx.x;
    __shared__ float sx[CIN];
    __shared__ float sa[CIN];
    float inv = 1.0f / fmaxf(deg[n], 1.0f);
    if (c < CIN) {
        sx[c] = x[n * CIN + c];
        sa[c] = agg1[n * CIN + c] * inv;
    }
    __syncthreads();
    float acc = b1l[c];
    #pragma unroll 5
    for (int k = 0; k < CIN; ++k) {
        acc = fmaf(sa[k], w1l[k * CH + c], acc);
        acc = fmaf(sx[k], w1r[k * CH + c], acc);
    }
    h[n * CH + c] = acc;
}

// ---------------------------------------------------------------------------
// Stage 4: agg2[dst] += h[src], only for dst < NOUT (output rows only)
__global__ void scatter2(const float* __restrict__ h,
                         const int* __restrict__ src,
                         const int* __restrict__ dst,
                         float* __restrict__ agg2) {
    int idx = blockIdx.x * blockDim.x + threadIdx.x;   // < E*CH = 102.4M < 2^31
    if (idx >= E * CH) return;
    int e = idx >> 7;          // /128
    int f = idx & 127;         // %128
    int d = dst[e];
    if (d >= NOUT) return;
    int s = src[e];
    atomicAdd(&agg2[d * CH + f], h[s * CH + f]);
}

// ---------------------------------------------------------------------------
// Stage 5: out[n] = log_softmax( (agg2[n]/deg) @ w2_l + h[n] @ w2_r + b2_l )
// One 64-thread wave per node; 47 active channels; shuffle reductions for
// max and sum(exp) within the wave.
__global__ __launch_bounds__(64) void layer2(
        const float* __restrict__ h, const float* __restrict__ agg2,
        const float* __restrict__ deg,
        const float* __restrict__ w2l, const float* __restrict__ b2l,
        const float* __restrict__ w2r,
        float* __restrict__ out) {
    int n = blockIdx.x;
    int t = threadIdx.x;
    __shared__ float sh[CH];
    __shared__ float sa[CH];
    float inv = 1.0f / fmaxf(deg[n], 1.0f);
    sh[t]      = h[n * CH + t];
    sh[t + 64] = h[n * CH + t + 64];
    sa[t]      = agg2[n * CH + t] * inv;
    sa[t + 64] = agg2[n * CH + t + 64] * inv;
    __syncthreads();

    float acc = -INFINITY;
    if (t < COUT) {
        acc = b2l[t];
        #pragma unroll 8
        for (int k = 0; k < CH; ++k) {
            acc = fmaf(sa[k], w2l[k * COUT + t], acc);
            acc = fmaf(sh[k], w2r[k * COUT + t], acc);
        }
    }
    // wave-wide max (64 lanes; inactive lanes hold -inf)
    float m = acc;
    #pragma unroll
    for (int off = 32; off > 0; off >>= 1)
        m = fmaxf(m, __shfl_xor(m, off, 64));
    float ex = (t < COUT) ? expf(acc - m) : 0.0f;
    float s = ex;
    #pragma unroll
    for (int off = 32; off > 0; off >>= 1)
        s += __shfl_xor(s, off, 64);
    if (t < COUT)
        out[n * COUT + t] = acc - m - logf(s);
}

// ---------------------------------------------------------------------------
extern "C" void kernel_launch(void* const* d_in, const int* in_sizes, int n_in,
                              void* d_out, int out_size, void* d_ws, size_t ws_size,
                              hipStream_t stream) {
    const float* x   = (const float*)d_in[0];
    const int*   ei  = (const int*)d_in[1];   // [2, E]: row 0 = src, row 1 = dst
    const int*   src = ei;
    const int*   dst = ei + E;
    // d_in[2] = original_size (unused; hardcoded NOUT)
    const float* w1l = (const float*)d_in[3];
    const float* b1l = (const float*)d_in[4];
    const float* w1r = (const float*)d_in[5];
    const float* w2l = (const float*)d_in[6];
    const float* b2l = (const float*)d_in[7];
    const float* w2r = (const float*)d_in[8];
    float* out = (float*)d_out;

    // workspace layout (floats): [agg1 N*CIN | deg N | agg2 NOUT*CH | h N*CH]
    float* ws   = (float*)d_ws;
    float* agg1 = ws;
    float* deg  = agg1 + (size_t)N * CIN;
    float* agg2 = deg + N;
    float* h    = agg2 + (size_t)NOUT * CH;

    // zero the accumulators (agg1, deg, agg2) in one contiguous memset
    size_t zero_floats = (size_t)N * CIN + N + (size_t)NOUT * CH;
    hipMemsetAsync(d_ws, 0, zero_floats * sizeof(float), stream);

    deg_kernel<<<(E + 255) / 256, 256, 0, stream>>>(dst, deg);
    scatter1<<<(E * CIN + 255) / 256, 256, 0, stream>>>(x, src, dst, agg1);
    layer1<<<N, 128, 0, stream>>>(x, agg1, deg, w1l, b1l, w1r, h);
    scatter2<<<(E * CH + 255) / 256, 256, 0, stream>>>(h, src, dst, agg2);
    layer2<<<NOUT, 64, 0, stream>>>(h, agg2, deg, w2l, b2l, w2r, out);
}

// Round 3
// 633.452 us; speedup vs baseline: 1.4018x; 1.4018x over previous
//
#include <hip/hip_runtime.h>
#include <math.h>

// Problem constants (from reference setup_inputs)
constexpr int N    = 50000;   // nodes
constexpr int E    = 800000;  // edges
constexpr int CIN  = 100;     // input channels
constexpr int CH   = 128;     // hidden channels
constexpr int COUT = 47;      // output channels
constexpr int NOUT = 25000;   // original_size (rows emitted)
constexpr int CP   = 48;      // COUT padded (alignment / lane mapping)

// ---------------------------------------------------------------------------
// CSR build stage 1: in-degree histogram (int atomics, low contention)
__global__ void hist_kernel(const int* __restrict__ dst, int* __restrict__ cnt) {
    int i = blockIdx.x * blockDim.x + threadIdx.x;
    if (i < E) atomicAdd(&cnt[dst[i]], 1);
}

// CSR build stage 2: exclusive prefix sum over 50k counts (single block)
__global__ __launch_bounds__(512) void scan_kernel(const int* __restrict__ cnt,
        int* __restrict__ row_ptr, int* __restrict__ cursor) {
    __shared__ int sums[512];
    const int CHUNK = 98;                 // 512*98 = 50176 >= N
    int t = threadIdx.x;
    int lo = t * CHUNK, hi = min(lo + CHUNK, N);
    int s = 0;
    for (int i = lo; i < hi; ++i) s += cnt[i];
    sums[t] = s;
    __syncthreads();
    for (int off = 1; off < 512; off <<= 1) {
        int v = sums[t];
        int u = (t >= off) ? sums[t - off] : 0;
        __syncthreads();
        sums[t] = v + u;
        __syncthreads();
    }
    int run = (t > 0) ? sums[t - 1] : 0;   // exclusive prefix of this chunk
    for (int i = lo; i < hi; ++i) {
        int c = cnt[i];
        row_ptr[i] = run;
        cursor[i]  = run;
        run += c;
    }
    if (t == 511) row_ptr[N] = E;
}

// CSR build stage 3: bucket-fill edge sources (int atomics on cursors)
__global__ void fill_kernel(const int* __restrict__ src, const int* __restrict__ dst,
        int* __restrict__ cursor, int* __restrict__ col) {
    int i = blockIdx.x * blockDim.x + threadIdx.x;
    if (i < E) {
        int d = dst[i];
        int p = atomicAdd(&cursor[d], 1);
        col[p] = src[i];
    }
}

// ---------------------------------------------------------------------------
// gather1: agg1[n] = mean_{s in N(n)} x[s]   (row-major [N][CIN], no atomics)
// thread f<100 owns feature f; 8 nodes per block; 4-way unrolled j-loop for MLP.
__global__ __launch_bounds__(128) void gather1_kernel(const float* __restrict__ x,
        const int* __restrict__ row_ptr, const int* __restrict__ col,
        float* __restrict__ agg1) {
    int f = threadIdx.x;
    int base = blockIdx.x * 8;
    if (f >= CIN) return;
    for (int r = 0; r < 8; ++r) {
        int n = base + r;
        int b = row_ptr[n], e = row_ptr[n + 1];
        float inv = 1.0f / (float)max(e - b, 1);
        float a0 = 0.f, a1 = 0.f, a2 = 0.f, a3 = 0.f;
        int j = b;
        for (; j + 3 < e; j += 4) {
            int s0 = col[j], s1 = col[j + 1], s2 = col[j + 2], s3 = col[j + 3];
            a0 += x[s0 * CIN + f];
            a1 += x[s1 * CIN + f];
            a2 += x[s2 * CIN + f];
            a3 += x[s3 * CIN + f];
        }
        for (; j < e; ++j) a0 += x[col[j] * CIN + f];
        agg1[n * CIN + f] = ((a0 + a1) + (a2 + a3)) * inv;
    }
}

// ---------------------------------------------------------------------------
// gemm1: h = mean @ w1l + x @ w1r + b1l, stored transposed hT[CH][N].
// Block = 128 thr (2 waves) = 64 nodes; lane r owns node base+r, wave half owns
// 64 output channels. Features staged in LDS (stride 101 -> conflict-free);
// weight rows are wave-uniform -> scalar loads; 64 reg accumulators.
// Grid rounded up; staging clamped and stores guarded for the partial block.
__global__ __launch_bounds__(128) void gemm1_kernel(const float* __restrict__ agg1,
        const float* __restrict__ x,
        const float* __restrict__ w1l, const float* __restrict__ b1l,
        const float* __restrict__ w1r, float* __restrict__ hT) {
    __shared__ float feat[64 * 101];
    int t = threadIdx.x;
    int base = blockIdx.x * 64;
    int r = t & 63, half = t >> 6;
    int c0 = half * 64;
    int limit = (N - base < 64 ? N - base : 64) * CIN;   // valid flat elements
    float acc[64];
    #pragma unroll
    for (int c = 0; c < 64; ++c) acc[c] = b1l[c0 + c];

    // phase A: mean rows (flat coalesced copy into padded LDS)
    for (int i = t; i < 64 * CIN; i += 128)
        feat[(i / CIN) * 101 + (i % CIN)] =
            (i < limit) ? agg1[(size_t)base * CIN + i] : 0.0f;
    __syncthreads();
    const float* frow = feat + r * 101;
    for (int k = 0; k < CIN; ++k) {
        float fv = frow[k];
        const float* w = w1l + k * CH + c0;   // wave-uniform row -> s_load
        #pragma unroll
        for (int c = 0; c < 64; ++c) acc[c] = fmaf(fv, w[c], acc[c]);
    }
    __syncthreads();
    // phase B: self rows
    for (int i = t; i < 64 * CIN; i += 128)
        feat[(i / CIN) * 101 + (i % CIN)] =
            (i < limit) ? x[(size_t)base * CIN + i] : 0.0f;
    __syncthreads();
    for (int k = 0; k < CIN; ++k) {
        float fv = frow[k];
        const float* w = w1r + k * CH + c0;
        #pragma unroll
        for (int c = 0; c < 64; ++c) acc[c] = fmaf(fv, w[c], acc[c]);
    }
    int n = base + r;
    if (n < N) {
        #pragma unroll
        for (int c = 0; c < 64; ++c)
            hT[(size_t)(c0 + c) * N + n] = acc[c];   // lane-coalesced stores
    }
}

// ---------------------------------------------------------------------------
// gemm2 (transform-first layer 2): gsrc[n] = h[n] @ w2l for ALL n;
// gself[n] = h[n] @ w2r + b2l for n < NOUT. Row-major padded-48 outputs via
// LDS transpose so stores are coalesced and the later gather reads 192B rows.
__global__ __launch_bounds__(64) void gemm2_kernel(const float* __restrict__ hT,
        const float* __restrict__ w2l, const float* __restrict__ b2l,
        const float* __restrict__ w2r,
        float* __restrict__ gsrc, float* __restrict__ gself) {
    __shared__ float feat[64 * 129];
    __shared__ float T[64 * 49];
    int l = threadIdx.x;
    int base = blockIdx.x * 64;
    int nn = base + l < N ? base + l : N - 1;   // clamp staging for partial block
    // stage h rows from hT: per k, 64 lanes read 256B coalesced
    for (int k = 0; k < CH; ++k)
        feat[l * 129 + k] = hT[(size_t)k * N + nn];
    __syncthreads();
    const float* frow = feat + l * 129;
    {
        float acc[CP];
        #pragma unroll
        for (int c = 0; c < CP; ++c) acc[c] = 0.0f;
        for (int k = 0; k < CH; ++k) {
            float fv = frow[k];
            const float* w = w2l + k * COUT;   // uniform -> scalar loads
            #pragma unroll
            for (int c = 0; c < COUT; ++c) acc[c] = fmaf(fv, w[c], acc[c]);
        }
        #pragma unroll
        for (int c = 0; c < CP; ++c) T[l * 49 + c] = acc[c];
        __syncthreads();
        int lim = (N - base < 64 ? N - base : 64) * CP;
        for (int i = l; i < lim; i += 64)
            gsrc[(size_t)base * CP + i] = T[(i / CP) * 49 + (i % CP)];
    }
    if (base < NOUT) {
        __syncthreads();   // protect T reuse (block-uniform branch)
        float acc[CP];
        #pragma unroll
        for (int c = 0; c < CP; ++c) acc[c] = (c < COUT) ? b2l[c] : 0.0f;
        for (int k = 0; k < CH; ++k) {
            float fv = frow[k];
            const float* w = w2r + k * COUT;
            #pragma unroll
            for (int c = 0; c < COUT; ++c) acc[c] = fmaf(fv, w[c], acc[c]);
        }
        #pragma unroll
        for (int c = 0; c < CP; ++c) T[l * 49 + c] = acc[c];
        __syncthreads();
        int lim = (NOUT - base < 64 ? NOUT - base : 64) * CP;
        for (int i = l; i < lim; i += 64)
            gself[(size_t)base * CP + i] = T[(i / CP) * 49 + (i % CP)];
    }
}

// ---------------------------------------------------------------------------
// final: out[n] = log_softmax( mean_{s in N(n)} gsrc[s] + gself[n] )
// One wave per output node; lanes own channels; 192B-row gathers.
__global__ __launch_bounds__(64) void final_kernel(const float* __restrict__ gsrc,
        const float* __restrict__ gself, const int* __restrict__ row_ptr,
        const int* __restrict__ col, float* __restrict__ out) {
    int n = blockIdx.x;
    int c = threadIdx.x;
    int b = row_ptr[n], e = row_ptr[n + 1];
    float inv = 1.0f / (float)max(e - b, 1);
    float a0 = 0.f, a1 = 0.f;
    if (c < CP) {
        int j = b;
        for (; j + 1 < e; j += 2) {
            a0 += gsrc[(size_t)col[j] * CP + c];
            a1 += gsrc[(size_t)col[j + 1] * CP + c];
        }
        if (j < e) a0 += gsrc[(size_t)col[j] * CP + c];
    }
    float val = (c < COUT) ? ((a0 + a1) * inv + gself[(size_t)n * CP + c]) : -INFINITY;
    float m = val;
    #pragma unroll
    for (int off = 32; off > 0; off >>= 1) m = fmaxf(m, __shfl_xor(m, off, 64));
    float ex = (c < COUT) ? expf(val - m) : 0.f;
    float ssum = ex;
    #pragma unroll
    for (int off = 32; off > 0; off >>= 1) ssum += __shfl_xor(ssum, off, 64);
    if (c < COUT) out[(size_t)n * COUT + c] = val - m - logf(ssum);
}

// ---------------------------------------------------------------------------
extern "C" void kernel_launch(void* const* d_in, const int* in_sizes, int n_in,
                              void* d_out, int out_size, void* d_ws, size_t ws_size,
                              hipStream_t stream) {
    const float* x   = (const float*)d_in[0];
    const int*   ei  = (const int*)d_in[1];   // [2, E]: row 0 = src, row 1 = dst
    const int*   src = ei;
    const int*   dst = ei + E;
    const float* w1l = (const float*)d_in[3];
    const float* b1l = (const float*)d_in[4];
    const float* w1r = (const float*)d_in[5];
    const float* w2l = (const float*)d_in[6];
    const float* b2l = (const float*)d_in[7];
    const float* w2r = (const float*)d_in[8];
    float* out = (float*)d_out;

    // workspace layout: ints [cnt N | row_ptr N+1 | cursor N | col E] (pad to 16B)
    // then floats [agg1 N*CIN  (later reused as gsrc N*CP + gself NOUT*CP)] [hT CH*N]
    int* cnt     = (int*)d_ws;
    int* row_ptr = cnt + N;
    int* cursor  = row_ptr + N + 1;
    int* col     = cursor + N;
    size_t intWords = (size_t)N + (N + 1) + N + E;
    intWords = (intWords + 3) & ~(size_t)3;
    float* agg1  = (float*)d_ws + intWords;
    float* hT    = agg1 + (size_t)N * CIN;
    float* gsrc  = agg1;                          // alias: agg1 dead after gemm1
    float* gself = gsrc + (size_t)N * CP;
    // total ws: ~49.4 MB (< 58.6 MB proven available in round 1)

    hipMemsetAsync(cnt, 0, (size_t)N * sizeof(int), stream);
    hist_kernel <<<(E + 255) / 256, 256, 0, stream>>>(dst, cnt);
    scan_kernel <<<1, 512, 0, stream>>>(cnt, row_ptr, cursor);
    fill_kernel <<<(E + 255) / 256, 256, 0, stream>>>(src, dst, cursor, col);
    gather1_kernel<<<N / 8,        128, 0, stream>>>(x, row_ptr, col, agg1);
    gemm1_kernel  <<<(N + 63) / 64, 128, 0, stream>>>(agg1, x, w1l, b1l, w1r, hT);
    gemm2_kernel  <<<(N + 63) / 64,  64, 0, stream>>>(hT, w2l, b2l, w2r, gsrc, gself);
    final_kernel  <<<NOUT,           64, 0, stream>>>(gsrc, gself, row_ptr, col, out);
}

// Round 4
// 500.289 us; speedup vs baseline: 1.7749x; 1.2662x over previous
//
#include <hip/hip_runtime.h>
#include <math.h>

// Problem constants (from reference setup_inputs)
constexpr int N    = 50000;   // nodes
constexpr int E    = 800000;  // edges
constexpr int CIN  = 100;     // input channels
constexpr int CH   = 128;     // hidden channels
constexpr int COUT = 47;      // output channels
constexpr int NOUT = 25000;   // original_size (rows emitted)
constexpr int CP   = 48;      // COUT padded (alignment / lane mapping)

// ---------------------------------------------------------------------------
// CSR build stage 1: in-degree histogram (int atomics, low contention)
__global__ void hist_kernel(const int* __restrict__ dst, int* __restrict__ cnt) {
    int i = blockIdx.x * blockDim.x + threadIdx.x;
    if (i < E) atomicAdd(&cnt[dst[i]], 1);
}

// CSR build stage 2: exclusive prefix sum over 50k counts (single block)
__global__ __launch_bounds__(512) void scan_kernel(const int* __restrict__ cnt,
        int* __restrict__ row_ptr, int* __restrict__ cursor) {
    __shared__ int sums[512];
    const int CHUNK = 98;                 // 512*98 = 50176 >= N
    int t = threadIdx.x;
    int lo = t * CHUNK, hi = min(lo + CHUNK, N);
    int s = 0;
    for (int i = lo; i < hi; ++i) s += cnt[i];
    sums[t] = s;
    __syncthreads();
    for (int off = 1; off < 512; off <<= 1) {
        int v = sums[t];
        int u = (t >= off) ? sums[t - off] : 0;
        __syncthreads();
        sums[t] = v + u;
        __syncthreads();
    }
    int run = (t > 0) ? sums[t - 1] : 0;   // exclusive prefix of this chunk
    for (int i = lo; i < hi; ++i) {
        int c = cnt[i];
        row_ptr[i] = run;
        cursor[i]  = run;
        run += c;
    }
    if (t == 511) row_ptr[N] = E;
}

// CSR build stage 3: bucket-fill edge sources (int atomics on cursors)
__global__ void fill_kernel(const int* __restrict__ src, const int* __restrict__ dst,
        int* __restrict__ cursor, int* __restrict__ col) {
    int i = blockIdx.x * blockDim.x + threadIdx.x;
    if (i < E) {
        int d = dst[i];
        int p = atomicAdd(&cursor[d], 1);
        col[p] = src[i];
    }
}

// ---------------------------------------------------------------------------
// gather1: agg1[n] = mean_{s in N(n)} x[s]   (row-major [N][CIN], no atomics)
// thread f<100 owns feature f; 8 nodes per block; 4-way unrolled j-loop for MLP.
__global__ __launch_bounds__(128) void gather1_kernel(const float* __restrict__ x,
        const int* __restrict__ row_ptr, const int* __restrict__ col,
        float* __restrict__ agg1) {
    int f = threadIdx.x;
    int base = blockIdx.x * 8;
    if (f >= CIN) return;
    for (int r = 0; r < 8; ++r) {
        int n = base + r;
        int b = row_ptr[n], e = row_ptr[n + 1];
        float inv = 1.0f / (float)max(e - b, 1);
        float a0 = 0.f, a1 = 0.f, a2 = 0.f, a3 = 0.f;
        int j = b;
        for (; j + 3 < e; j += 4) {
            int s0 = col[j], s1 = col[j + 1], s2 = col[j + 2], s3 = col[j + 3];
            a0 += x[s0 * CIN + f];
            a1 += x[s1 * CIN + f];
            a2 += x[s2 * CIN + f];
            a3 += x[s3 * CIN + f];
        }
        for (; j < e; ++j) a0 += x[col[j] * CIN + f];
        agg1[n * CIN + f] = ((a0 + a1) + (a2 + a3)) * inv;
    }
}

// ---------------------------------------------------------------------------
// gemm1: h = mean @ w1l + x @ w1r + b1l, stored transposed hT[CH][N].
// Block = 128 thr (2 waves) = 64 nodes; lane r owns node base+r, wave half owns
// 64 output channels. Features staged in LDS (stride 101 -> conflict-free).
// KEY FIX (R4): c0 is wave-uniform in VALUE but derived from threadIdx, so
// divergence analysis treated weight addresses as divergent -> 64 per-lane
// global_load_dword per k-iter (R3 profile: VALUBusy 9%). readfirstlane makes
// uniformity explicit -> weights via scalar s_load, inner loop is pure v_fma.
__global__ __launch_bounds__(128) void gemm1_kernel(const float* __restrict__ agg1,
        const float* __restrict__ x,
        const float* __restrict__ w1l, const float* __restrict__ b1l,
        const float* __restrict__ w1r, float* __restrict__ hT) {
    __shared__ float feat[64 * 101];
    int t = threadIdx.x;
    int base = blockIdx.x * 64;
    int r = t & 63;
    int c0 = __builtin_amdgcn_readfirstlane((t >> 6) * 64);  // wave-uniform, now provably
    int limit = (N - base < 64 ? N - base : 64) * CIN;   // valid flat elements
    float acc[64];
    #pragma unroll
    for (int c = 0; c < 64; ++c) acc[c] = b1l[c0 + c];

    // phase A: mean rows (flat coalesced copy into padded LDS)
    for (int i = t; i < 64 * CIN; i += 128)
        feat[(i / CIN) * 101 + (i % CIN)] =
            (i < limit) ? agg1[(size_t)base * CIN + i] : 0.0f;
    __syncthreads();
    const float* frow = feat + r * 101;
    for (int k = 0; k < CIN; ++k) {
        float fv = frow[k];
        const float* w = w1l + k * CH + c0;   // uniform base -> s_load batches
        #pragma unroll
        for (int c = 0; c < 64; ++c) acc[c] = fmaf(fv, w[c], acc[c]);
    }
    __syncthreads();
    // phase B: self rows
    for (int i = t; i < 64 * CIN; i += 128)
        feat[(i / CIN) * 101 + (i % CIN)] =
            (i < limit) ? x[(size_t)base * CIN + i] : 0.0f;
    __syncthreads();
    for (int k = 0; k < CIN; ++k) {
        float fv = frow[k];
        const float* w = w1r + k * CH + c0;
        #pragma unroll
        for (int c = 0; c < 64; ++c) acc[c] = fmaf(fv, w[c], acc[c]);
    }
    int n = base + r;
    if (n < N) {
        #pragma unroll
        for (int c = 0; c < 64; ++c)
            hT[(size_t)(c0 + c) * N + n] = acc[c];   // lane-coalesced stores
    }
}

// ---------------------------------------------------------------------------
// gemm2 (transform-first layer 2): gsrc[n] = h[n] @ w2l for ALL n;
// gself[n] = h[n] @ w2r + b2l for n < NOUT. Row-major padded-48 outputs via
// LDS transpose so stores are coalesced and the later gather reads 192B rows.
// (weight addresses here contain no tid -> already scalar loads)
__global__ __launch_bounds__(64) void gemm2_kernel(const float* __restrict__ hT,
        const float* __restrict__ w2l, const float* __restrict__ b2l,
        const float* __restrict__ w2r,
        float* __restrict__ gsrc, float* __restrict__ gself) {
    __shared__ float feat[64 * 129];
    __shared__ float T[64 * 49];
    int l = threadIdx.x;
    int base = blockIdx.x * 64;
    int nn = base + l < N ? base + l : N - 1;   // clamp staging for partial block
    // stage h rows from hT: per k, 64 lanes read 256B coalesced
    for (int k = 0; k < CH; ++k)
        feat[l * 129 + k] = hT[(size_t)k * N + nn];
    __syncthreads();
    const float* frow = feat + l * 129;
    {
        float acc[CP];
        #pragma unroll
        for (int c = 0; c < CP; ++c) acc[c] = 0.0f;
        for (int k = 0; k < CH; ++k) {
            float fv = frow[k];
            const float* w = w2l + k * COUT;   // uniform -> scalar loads
            #pragma unroll
            for (int c = 0; c < COUT; ++c) acc[c] = fmaf(fv, w[c], acc[c]);
        }
        #pragma unroll
        for (int c = 0; c < CP; ++c) T[l * 49 + c] = acc[c];
        __syncthreads();
        int lim = (N - base < 64 ? N - base : 64) * CP;
        for (int i = l; i < lim; i += 64)
            gsrc[(size_t)base * CP + i] = T[(i / CP) * 49 + (i % CP)];
    }
    if (base < NOUT) {
        __syncthreads();   // protect T reuse (block-uniform branch)
        float acc[CP];
        #pragma unroll
        for (int c = 0; c < CP; ++c) acc[c] = (c < COUT) ? b2l[c] : 0.0f;
        for (int k = 0; k < CH; ++k) {
            float fv = frow[k];
            const float* w = w2r + k * COUT;
            #pragma unroll
            for (int c = 0; c < COUT; ++c) acc[c] = fmaf(fv, w[c], acc[c]);
        }
        #pragma unroll
        for (int c = 0; c < CP; ++c) T[l * 49 + c] = acc[c];
        __syncthreads();
        int lim = (NOUT - base < 64 ? NOUT - base : 64) * CP;
        for (int i = l; i < lim; i += 64)
            gself[(size_t)base * CP + i] = T[(i / CP) * 49 + (i % CP)];
    }
}

// ---------------------------------------------------------------------------
// final: out[n] = log_softmax( mean_{s in N(n)} gsrc[s] + gself[n] )
// One wave per output node; lanes own channels; 192B-row gathers.
__global__ __launch_bounds__(64) void final_kernel(const float* __restrict__ gsrc,
        const float* __restrict__ gself, const int* __restrict__ row_ptr,
        const int* __restrict__ col, float* __restrict__ out) {
    int n = blockIdx.x;
    int c = threadIdx.x;
    int b = row_ptr[n], e = row_ptr[n + 1];
    float inv = 1.0f / (float)max(e - b, 1);
    float a0 = 0.f, a1 = 0.f;
    if (c < CP) {
        int j = b;
        for (; j + 1 < e; j += 2) {
            a0 += gsrc[(size_t)col[j] * CP + c];
            a1 += gsrc[(size_t)col[j + 1] * CP + c];
        }
        if (j < e) a0 += gsrc[(size_t)col[j] * CP + c];
    }
    float val = (c < COUT) ? ((a0 + a1) * inv + gself[(size_t)n * CP + c]) : -INFINITY;
    float m = val;
    #pragma unroll
    for (int off = 32; off > 0; off >>= 1) m = fmaxf(m, __shfl_xor(m, off, 64));
    float ex = (c < COUT) ? expf(val - m) : 0.f;
    float ssum = ex;
    #pragma unroll
    for (int off = 32; off > 0; off >>= 1) ssum += __shfl_xor(ssum, off, 64);
    if (c < COUT) out[(size_t)n * COUT + c] = val - m - logf(ssum);
}

// ---------------------------------------------------------------------------
extern "C" void kernel_launch(void* const* d_in, const int* in_sizes, int n_in,
                              void* d_out, int out_size, void* d_ws, size_t ws_size,
                              hipStream_t stream) {
    const float* x   = (const float*)d_in[0];
    const int*   ei  = (const int*)d_in[1];   // [2, E]: row 0 = src, row 1 = dst
    const int*   src = ei;
    const int*   dst = ei + E;
    const float* w1l = (const float*)d_in[3];
    const float* b1l = (const float*)d_in[4];
    const float* w1r = (const float*)d_in[5];
    const float* w2l = (const float*)d_in[6];
    const float* b2l = (const float*)d_in[7];
    const float* w2r = (const float*)d_in[8];
    float* out = (float*)d_out;

    // workspace layout: ints [cnt N | row_ptr N+1 | cursor N | col E] (pad to 16B)
    // then floats [agg1 N*CIN  (later reused as gsrc N*CP + gself NOUT*CP)] [hT CH*N]
    int* cnt     = (int*)d_ws;
    int* row_ptr = cnt + N;
    int* cursor  = row_ptr + N + 1;
    int* col     = cursor + N;
    size_t intWords = (size_t)N + (N + 1) + N + E;
    intWords = (intWords + 3) & ~(size_t)3;
    float* agg1  = (float*)d_ws + intWords;
    float* hT    = agg1 + (size_t)N * CIN;
    float* gsrc  = agg1;                          // alias: agg1 dead after gemm1
    float* gself = gsrc + (size_t)N * CP;
    // total ws: ~49.4 MB (< 58.6 MB proven available in round 1)

    hipMemsetAsync(cnt, 0, (size_t)N * sizeof(int), stream);
    hist_kernel <<<(E + 255) / 256, 256, 0, stream>>>(dst, cnt);
    scan_kernel <<<1, 512, 0, stream>>>(cnt, row_ptr, cursor);
    fill_kernel <<<(E + 255) / 256, 256, 0, stream>>>(src, dst, cursor, col);
    gather1_kernel<<<N / 8,        128, 0, stream>>>(x, row_ptr, col, agg1);
    gemm1_kernel  <<<(N + 63) / 64, 128, 0, stream>>>(agg1, x, w1l, b1l, w1r, hT);
    gemm2_kernel  <<<(N + 63) / 64,  64, 0, stream>>>(hT, w2l, b2l, w2r, gsrc, gself);
    final_kernel  <<<NOUT,           64, 0, stream>>>(gsrc, gself, row_ptr, col, out);
}

// Round 5
// 401.728 us; speedup vs baseline: 2.2104x; 1.2453x over previous
//
#include <hip/hip_runtime.h>
#include <math.h>

// Problem constants (from reference setup_inputs)
constexpr int N    = 50000;   // nodes
constexpr int E    = 800000;  // edges
constexpr int CIN  = 100;     // input channels
constexpr int CH   = 128;     // hidden channels
constexpr int COUT = 47;      // output channels
constexpr int NOUT = 25000;   // original_size (rows emitted)
constexpr int CP   = 48;      // COUT padded (alignment / lane mapping)
constexpr int NB   = (N + 255) / 256;   // 196 scan blocks

// ---------------------------------------------------------------------------
// CSR build stage 1: in-degree histogram (int atomics, low contention)
__global__ void hist_kernel(const int* __restrict__ dst, int* __restrict__ cnt) {
    int i = blockIdx.x * blockDim.x + threadIdx.x;
    if (i < E) atomicAdd(&cnt[dst[i]], 1);
}

// CSR build stage 2a: per-block exclusive scan of cnt (coalesced, parallel).
// R5: replaces the single-block serial scan (116 us, 0.09% occupancy, strided
// access) with a 3-pass parallel scan.
__global__ __launch_bounds__(256) void scan_blocks(const int* __restrict__ cnt,
        int* __restrict__ row_ptr, int* __restrict__ blkSum) {
    __shared__ int s[256];
    int t = threadIdx.x;
    int i = blockIdx.x * 256 + t;
    int v = (i < N) ? cnt[i] : 0;
    s[t] = v;
    __syncthreads();
    for (int off = 1; off < 256; off <<= 1) {
        int a = s[t];
        int u = (t >= off) ? s[t - off] : 0;
        __syncthreads();
        s[t] = a + u;
        __syncthreads();
    }
    if (i < N) row_ptr[i] = s[t] - v;          // local exclusive prefix
    if (t == 255) blkSum[blockIdx.x] = s[255]; // block total
}

// CSR build stage 2b: scan the 196 block sums (single tiny block)
__global__ __launch_bounds__(256) void scan_sums(int* __restrict__ blkSum,
        int* __restrict__ blkOff) {
    __shared__ int s[256];
    int t = threadIdx.x;
    int v = (t < NB) ? blkSum[t] : 0;
    s[t] = v;
    __syncthreads();
    for (int off = 1; off < 256; off <<= 1) {
        int a = s[t];
        int u = (t >= off) ? s[t - off] : 0;
        __syncthreads();
        s[t] = a + u;
        __syncthreads();
    }
    if (t < NB) blkOff[t] = s[t] - v;          // exclusive offsets
}

// CSR build stage 2c: apply block offsets; produce cursor copy; row_ptr[N]=E
__global__ __launch_bounds__(256) void scan_add(int* __restrict__ row_ptr,
        int* __restrict__ cursor, const int* __restrict__ blkOff) {
    int i = blockIdx.x * 256 + threadIdx.x;
    if (i < N) {
        int v = row_ptr[i] + blkOff[blockIdx.x];
        row_ptr[i] = v;
        cursor[i]  = v;
        if (i == N - 1) row_ptr[N] = E;
    }
}

// CSR build stage 3: bucket-fill edge sources (int atomics on cursors)
__global__ void fill_kernel(const int* __restrict__ src, const int* __restrict__ dst,
        int* __restrict__ cursor, int* __restrict__ col) {
    int i = blockIdx.x * blockDim.x + threadIdx.x;
    if (i < E) {
        int d = dst[i];
        int p = atomicAdd(&cursor[d], 1);
        col[p] = src[i];
    }
}

// ---------------------------------------------------------------------------
// gather1: agg1[n] = mean_{s in N(n)} x[s]   (row-major [N][CIN], no atomics)
// thread f<100 owns feature f; 8 nodes per block; 4-way unrolled j-loop for MLP.
__global__ __launch_bounds__(128) void gather1_kernel(const float* __restrict__ x,
        const int* __restrict__ row_ptr, const int* __restrict__ col,
        float* __restrict__ agg1) {
    int f = threadIdx.x;
    int base = blockIdx.x * 8;
    if (f >= CIN) return;
    for (int r = 0; r < 8; ++r) {
        int n = base + r;
        int b = row_ptr[n], e = row_ptr[n + 1];
        float inv = 1.0f / (float)max(e - b, 1);
        float a0 = 0.f, a1 = 0.f, a2 = 0.f, a3 = 0.f;
        int j = b;
        for (; j + 3 < e; j += 4) {
            int s0 = col[j], s1 = col[j + 1], s2 = col[j + 2], s3 = col[j + 3];
            a0 += x[s0 * CIN + f];
            a1 += x[s1 * CIN + f];
            a2 += x[s2 * CIN + f];
            a3 += x[s3 * CIN + f];
        }
        for (; j < e; ++j) a0 += x[col[j] * CIN + f];
        agg1[n * CIN + f] = ((a0 + a1) + (a2 + a3)) * inv;
    }
}

// ---------------------------------------------------------------------------
// gemm1: h = mean @ w1l + x @ w1r + b1l, stored transposed hT[CH][N].
// Block = 128 thr (2 waves) = 64 nodes; lane r owns node base+r, wave half owns
// 64 output channels. Features staged in LDS (stride 101 -> conflict-free).
// c0 via readfirstlane so weight addressing is provably wave-uniform -> s_load
// (R4 fix: 221 us -> off the top-5; VALUBusy was 9% due to per-lane loads).
__global__ __launch_bounds__(128) void gemm1_kernel(const float* __restrict__ agg1,
        const float* __restrict__ x,
        const float* __restrict__ w1l, const float* __restrict__ b1l,
        const float* __restrict__ w1r, float* __restrict__ hT) {
    __shared__ float feat[64 * 101];
    int t = threadIdx.x;
    int base = blockIdx.x * 64;
    int r = t & 63;
    int c0 = __builtin_amdgcn_readfirstlane((t >> 6) * 64);  // wave-uniform, provably
    int limit = (N - base < 64 ? N - base : 64) * CIN;   // valid flat elements
    float acc[64];
    #pragma unroll
    for (int c = 0; c < 64; ++c) acc[c] = b1l[c0 + c];

    // phase A: mean rows (flat coalesced copy into padded LDS)
    for (int i = t; i < 64 * CIN; i += 128)
        feat[(i / CIN) * 101 + (i % CIN)] =
            (i < limit) ? agg1[(size_t)base * CIN + i] : 0.0f;
    __syncthreads();
    const float* frow = feat + r * 101;
    for (int k = 0; k < CIN; ++k) {
        float fv = frow[k];
        const float* w = w1l + k * CH + c0;   // uniform base -> s_load batches
        #pragma unroll
        for (int c = 0; c < 64; ++c) acc[c] = fmaf(fv, w[c], acc[c]);
    }
    __syncthreads();
    // phase B: self rows
    for (int i = t; i < 64 * CIN; i += 128)
        feat[(i / CIN) * 101 + (i % CIN)] =
            (i < limit) ? x[(size_t)base * CIN + i] : 0.0f;
    __syncthreads();
    for (int k = 0; k < CIN; ++k) {
        float fv = frow[k];
        const float* w = w1r + k * CH + c0;
        #pragma unroll
        for (int c = 0; c < 64; ++c) acc[c] = fmaf(fv, w[c], acc[c]);
    }
    int n = base + r;
    if (n < N) {
        #pragma unroll
        for (int c = 0; c < 64; ++c)
            hT[(size_t)(c0 + c) * N + n] = acc[c];   // lane-coalesced stores
    }
}

// ---------------------------------------------------------------------------
// gemm2 (transform-first layer 2): gsrc[n] = h[n] @ w2l for ALL n;
// gself[n] = h[n] @ w2r + b2l for n < NOUT. Row-major padded-48 outputs via
// LDS transpose so stores are coalesced and the later gather reads 192B rows.
// (weight addresses here contain no tid -> already scalar loads)
__global__ __launch_bounds__(64) void gemm2_kernel(const float* __restrict__ hT,
        const float* __restrict__ w2l, const float* __restrict__ b2l,
        const float* __restrict__ w2r,
        float* __restrict__ gsrc, float* __restrict__ gself) {
    __shared__ float feat[64 * 129];
    __shared__ float T[64 * 49];
    int l = threadIdx.x;
    int base = blockIdx.x * 64;
    int nn = base + l < N ? base + l : N - 1;   // clamp staging for partial block
    // stage h rows from hT: per k, 64 lanes read 256B coalesced
    for (int k = 0; k < CH; ++k)
        feat[l * 129 + k] = hT[(size_t)k * N + nn];
    __syncthreads();
    const float* frow = feat + l * 129;
    {
        float acc[CP];
        #pragma unroll
        for (int c = 0; c < CP; ++c) acc[c] = 0.0f;
        for (int k = 0; k < CH; ++k) {
            float fv = frow[k];
            const float* w = w2l + k * COUT;   // uniform -> scalar loads
            #pragma unroll
            for (int c = 0; c < COUT; ++c) acc[c] = fmaf(fv, w[c], acc[c]);
        }
        #pragma unroll
        for (int c = 0; c < CP; ++c) T[l * 49 + c] = acc[c];
        __syncthreads();
        int lim = (N - base < 64 ? N - base : 64) * CP;
        for (int i = l; i < lim; i += 64)
            gsrc[(size_t)base * CP + i] = T[(i / CP) * 49 + (i % CP)];
    }
    if (base < NOUT) {
        __syncthreads();   // protect T reuse (block-uniform branch)
        float acc[CP];
        #pragma unroll
        for (int c = 0; c < CP; ++c) acc[c] = (c < COUT) ? b2l[c] : 0.0f;
        for (int k = 0; k < CH; ++k) {
            float fv = frow[k];
            const float* w = w2r + k * COUT;
            #pragma unroll
            for (int c = 0; c < COUT; ++c) acc[c] = fmaf(fv, w[c], acc[c]);
        }
        #pragma unroll
        for (int c = 0; c < CP; ++c) T[l * 49 + c] = acc[c];
        __syncthreads();
        int lim = (NOUT - base < 64 ? NOUT - base : 64) * CP;
        for (int i = l; i < lim; i += 64)
            gself[(size_t)base * CP + i] = T[(i / CP) * 49 + (i % CP)];
    }
}

// ---------------------------------------------------------------------------
// final: out[n] = log_softmax( mean_{s in N(n)} gsrc[s] + gself[n] )
// One wave per output node; lanes own channels; 192B-row gathers.
__global__ __launch_bounds__(64) void final_kernel(const float* __restrict__ gsrc,
        const float* __restrict__ gself, const int* __restrict__ row_ptr,
        const int* __restrict__ col, float* __restrict__ out) {
    int n = blockIdx.x;
    int c = threadIdx.x;
    int b = row_ptr[n], e = row_ptr[n + 1];
    float inv = 1.0f / (float)max(e - b, 1);
    float a0 = 0.f, a1 = 0.f;
    if (c < CP) {
        int j = b;
        for (; j + 1 < e; j += 2) {
            a0 += gsrc[(size_t)col[j] * CP + c];
            a1 += gsrc[(size_t)col[j + 1] * CP + c];
        }
        if (j < e) a0 += gsrc[(size_t)col[j] * CP + c];
    }
    float val = (c < COUT) ? ((a0 + a1) * inv + gself[(size_t)n * CP + c]) : -INFINITY;
    float m = val;
    #pragma unroll
    for (int off = 32; off > 0; off >>= 1) m = fmaxf(m, __shfl_xor(m, off, 64));
    float ex = (c < COUT) ? expf(val - m) : 0.f;
    float ssum = ex;
    #pragma unroll
    for (int off = 32; off > 0; off >>= 1) ssum += __shfl_xor(ssum, off, 64);
    if (c < COUT) out[(size_t)n * COUT + c] = val - m - logf(ssum);
}

// ---------------------------------------------------------------------------
extern "C" void kernel_launch(void* const* d_in, const int* in_sizes, int n_in,
                              void* d_out, int out_size, void* d_ws, size_t ws_size,
                              hipStream_t stream) {
    const float* x   = (const float*)d_in[0];
    const int*   ei  = (const int*)d_in[1];   // [2, E]: row 0 = src, row 1 = dst
    const int*   src = ei;
    const int*   dst = ei + E;
    const float* w1l = (const float*)d_in[3];
    const float* b1l = (const float*)d_in[4];
    const float* w1r = (const float*)d_in[5];
    const float* w2l = (const float*)d_in[6];
    const float* b2l = (const float*)d_in[7];
    const float* w2r = (const float*)d_in[8];
    float* out = (float*)d_out;

    // workspace layout: ints [cnt N | row_ptr N+1 | cursor N | blkSum NB | blkOff NB | col E]
    // then floats [agg1 N*CIN (later gsrc N*CP + gself NOUT*CP)] [hT CH*N]
    int* cnt     = (int*)d_ws;
    int* row_ptr = cnt + N;
    int* cursor  = row_ptr + N + 1;
    int* blkSum  = cursor + N;
    int* blkOff  = blkSum + NB;
    int* col     = blkOff + NB;
    size_t intWords = (size_t)N + (N + 1) + N + NB + NB + E;
    intWords = (intWords + 3) & ~(size_t)3;
    float* agg1  = (float*)d_ws + intWords;
    float* hT    = agg1 + (size_t)N * CIN;
    float* gsrc  = agg1;                          // alias: agg1 dead after gemm1
    float* gself = gsrc + (size_t)N * CP;
    // total ws: ~49.4 MB (< 58.6 MB proven available in round 1)

    hipMemsetAsync(cnt, 0, (size_t)N * sizeof(int), stream);
    hist_kernel <<<(E + 255) / 256, 256, 0, stream>>>(dst, cnt);
    scan_blocks <<<NB, 256, 0, stream>>>(cnt, row_ptr, blkSum);
    scan_sums   <<<1, 256, 0, stream>>>(blkSum, blkOff);
    scan_add    <<<NB, 256, 0, stream>>>(row_ptr, cursor, blkOff);
    fill_kernel <<<(E + 255) / 256, 256, 0, stream>>>(src, dst, cursor, col);
    gather1_kernel<<<N / 8,        128, 0, stream>>>(x, row_ptr, col, agg1);
    gemm1_kernel  <<<(N + 63) / 64, 128, 0, stream>>>(agg1, x, w1l, b1l, w1r, hT);
    gemm2_kernel  <<<(N + 63) / 64,  64, 0, stream>>>(hT, w2l, b2l, w2r, gsrc, gself);
    final_kernel  <<<NOUT,           64, 0, stream>>>(gsrc, gself, row_ptr, col, out);
}

// Round 6
// 375.268 us; speedup vs baseline: 2.3663x; 1.0705x over previous
//
#include <hip/hip_runtime.h>
#include <math.h>

// Problem constants (from reference setup_inputs)
constexpr int N    = 50000;   // nodes
constexpr int E    = 800000;  // edges
constexpr int CIN  = 100;     // input channels
constexpr int CH   = 128;     // hidden channels
constexpr int COUT = 47;      // output channels
constexpr int NOUT = 25000;   // original_size (rows emitted)
constexpr int CP   = 48;      // COUT padded (alignment / lane mapping)
constexpr int NB   = (N + 255) / 256;   // 196 scan blocks

// ---------------------------------------------------------------------------
// CSR build stage 1: in-degree histogram (int atomics, low contention)
__global__ void hist_kernel(const int* __restrict__ dst, int* __restrict__ cnt) {
    int i = blockIdx.x * blockDim.x + threadIdx.x;
    if (i < E) atomicAdd(&cnt[dst[i]], 1);
}

// CSR build stage 2a: per-block exclusive scan of cnt (coalesced, parallel)
__global__ __launch_bounds__(256) void scan_blocks(const int* __restrict__ cnt,
        int* __restrict__ row_ptr, int* __restrict__ blkSum) {
    __shared__ int s[256];
    int t = threadIdx.x;
    int i = blockIdx.x * 256 + t;
    int v = (i < N) ? cnt[i] : 0;
    s[t] = v;
    __syncthreads();
    for (int off = 1; off < 256; off <<= 1) {
        int a = s[t];
        int u = (t >= off) ? s[t - off] : 0;
        __syncthreads();
        s[t] = a + u;
        __syncthreads();
    }
    if (i < N) row_ptr[i] = s[t] - v;          // local exclusive prefix
    if (t == 255) blkSum[blockIdx.x] = s[255]; // block total
}

// CSR build stage 2b: scan the 196 block sums (single tiny block)
__global__ __launch_bounds__(256) void scan_sums(int* __restrict__ blkSum,
        int* __restrict__ blkOff) {
    __shared__ int s[256];
    int t = threadIdx.x;
    int v = (t < NB) ? blkSum[t] : 0;
    s[t] = v;
    __syncthreads();
    for (int off = 1; off < 256; off <<= 1) {
        int a = s[t];
        int u = (t >= off) ? s[t - off] : 0;
        __syncthreads();
        s[t] = a + u;
        __syncthreads();
    }
    if (t < NB) blkOff[t] = s[t] - v;          // exclusive offsets
}

// CSR build stage 2c: apply block offsets; produce cursor copy; row_ptr[N]=E
__global__ __launch_bounds__(256) void scan_add(int* __restrict__ row_ptr,
        int* __restrict__ cursor, const int* __restrict__ blkOff) {
    int i = blockIdx.x * 256 + threadIdx.x;
    if (i < N) {
        int v = row_ptr[i] + blkOff[blockIdx.x];
        row_ptr[i] = v;
        cursor[i]  = v;
        if (i == N - 1) row_ptr[N] = E;
    }
}

// CSR build stage 3: bucket-fill edge sources (int atomics on cursors)
__global__ void fill_kernel(const int* __restrict__ src, const int* __restrict__ dst,
        int* __restrict__ cursor, int* __restrict__ col) {
    int i = blockIdx.x * blockDim.x + threadIdx.x;
    if (i < E) {
        int d = dst[i];
        int p = atomicAdd(&cursor[d], 1);
        col[p] = src[i];
    }
}

// ---------------------------------------------------------------------------
// gather1: agg1[n] = mean_{s in N(n)} x[s]   (row-major [N][CIN], no atomics)
// thread f<100 owns feature f; 8 nodes per block; 4-way unrolled j-loop for MLP.
__global__ __launch_bounds__(128) void gather1_kernel(const float* __restrict__ x,
        const int* __restrict__ row_ptr, const int* __restrict__ col,
        float* __restrict__ agg1) {
    int f = threadIdx.x;
    int base = blockIdx.x * 8;
    if (f >= CIN) return;
    for (int r = 0; r < 8; ++r) {
        int n = base + r;
        int b = row_ptr[n], e = row_ptr[n + 1];
        float inv = 1.0f / (float)max(e - b, 1);
        float a0 = 0.f, a1 = 0.f, a2 = 0.f, a3 = 0.f;
        int j = b;
        for (; j + 3 < e; j += 4) {
            int s0 = col[j], s1 = col[j + 1], s2 = col[j + 2], s3 = col[j + 3];
            a0 += x[s0 * CIN + f];
            a1 += x[s1 * CIN + f];
            a2 += x[s2 * CIN + f];
            a3 += x[s3 * CIN + f];
        }
        for (; j < e; ++j) a0 += x[col[j] * CIN + f];
        agg1[n * CIN + f] = ((a0 + a1) + (a2 + a3)) * inv;
    }
}

// ---------------------------------------------------------------------------
// gemm1: h = mean @ w1l + x @ w1r + b1l, stored transposed hT[CH][N].
// R6: 256 thr = 4 waves per 64-node tile; wave w owns 32 channels (acc[32]).
// R5 profile showed 1.5 waves/SIMD (grid 782 x 2 waves) -> SMEM-latency-bound
// at VALUBusy 20%. Doubling waves (3128, ~3/SIMD) + halving per-wave regs
// hides the ~200cyc weight s_load behind other waves' 64-cyc FMA bursts.
// c0 via readfirstlane keeps weight addressing provably wave-uniform (R4 fix).
__global__ __launch_bounds__(256) void gemm1_kernel(const float* __restrict__ agg1,
        const float* __restrict__ x,
        const float* __restrict__ w1l, const float* __restrict__ b1l,
        const float* __restrict__ w1r, float* __restrict__ hT) {
    __shared__ float feat[64 * 101];
    int t = threadIdx.x;
    int base = blockIdx.x * 64;
    int r = t & 63;
    int c0 = __builtin_amdgcn_readfirstlane((t >> 6) * 32);  // wave-uniform, provably
    int limit = (N - base < 64 ? N - base : 64) * CIN;   // valid flat elements
    float acc[32];
    #pragma unroll
    for (int c = 0; c < 32; ++c) acc[c] = b1l[c0 + c];

    // phase A: mean rows (flat coalesced copy into padded LDS)
    for (int i = t; i < 64 * CIN; i += 256)
        feat[(i / CIN) * 101 + (i % CIN)] =
            (i < limit) ? agg1[(size_t)base * CIN + i] : 0.0f;
    __syncthreads();
    const float* frow = feat + r * 101;
    for (int k = 0; k < CIN; ++k) {
        float fv = frow[k];
        const float* w = w1l + k * CH + c0;   // uniform base -> s_load batches
        #pragma unroll
        for (int c = 0; c < 32; ++c) acc[c] = fmaf(fv, w[c], acc[c]);
    }
    __syncthreads();
    // phase B: self rows
    for (int i = t; i < 64 * CIN; i += 256)
        feat[(i / CIN) * 101 + (i % CIN)] =
            (i < limit) ? x[(size_t)base * CIN + i] : 0.0f;
    __syncthreads();
    for (int k = 0; k < CIN; ++k) {
        float fv = frow[k];
        const float* w = w1r + k * CH + c0;
        #pragma unroll
        for (int c = 0; c < 32; ++c) acc[c] = fmaf(fv, w[c], acc[c]);
    }
    int n = base + r;
    if (n < N) {
        #pragma unroll
        for (int c = 0; c < 32; ++c)
            hT[(size_t)(c0 + c) * N + n] = acc[c];   // lane-coalesced stores
    }
}

// ---------------------------------------------------------------------------
// gemm2 (transform-first layer 2): gsrc[n] = h[n] @ w2l for ALL n;
// gself[n] = h[n] @ w2r + b2l for n < NOUT. Row-major padded-48 outputs via
// LDS transpose so stores are coalesced and the later gather reads 192B rows.
// (weight addresses here contain no tid -> already scalar loads)
__global__ __launch_bounds__(64) void gemm2_kernel(const float* __restrict__ hT,
        const float* __restrict__ w2l, const float* __restrict__ b2l,
        const float* __restrict__ w2r,
        float* __restrict__ gsrc, float* __restrict__ gself) {
    __shared__ float feat[64 * 129];
    __shared__ float T[64 * 49];
    int l = threadIdx.x;
    int base = blockIdx.x * 64;
    int nn = base + l < N ? base + l : N - 1;   // clamp staging for partial block
    // stage h rows from hT: per k, 64 lanes read 256B coalesced
    for (int k = 0; k < CH; ++k)
        feat[l * 129 + k] = hT[(size_t)k * N + nn];
    __syncthreads();
    const float* frow = feat + l * 129;
    {
        float acc[CP];
        #pragma unroll
        for (int c = 0; c < CP; ++c) acc[c] = 0.0f;
        for (int k = 0; k < CH; ++k) {
            float fv = frow[k];
            const float* w = w2l + k * COUT;   // uniform -> scalar loads
            #pragma unroll
            for (int c = 0; c < COUT; ++c) acc[c] = fmaf(fv, w[c], acc[c]);
        }
        #pragma unroll
        for (int c = 0; c < CP; ++c) T[l * 49 + c] = acc[c];
        __syncthreads();
        int lim = (N - base < 64 ? N - base : 64) * CP;
        for (int i = l; i < lim; i += 64)
            gsrc[(size_t)base * CP + i] = T[(i / CP) * 49 + (i % CP)];
    }
    if (base < NOUT) {
        __syncthreads();   // protect T reuse (block-uniform branch)
        float acc[CP];
        #pragma unroll
        for (int c = 0; c < CP; ++c) acc[c] = (c < COUT) ? b2l[c] : 0.0f;
        for (int k = 0; k < CH; ++k) {
            float fv = frow[k];
            const float* w = w2r + k * COUT;
            #pragma unroll
            for (int c = 0; c < COUT; ++c) acc[c] = fmaf(fv, w[c], acc[c]);
        }
        #pragma unroll
        for (int c = 0; c < CP; ++c) T[l * 49 + c] = acc[c];
        __syncthreads();
        int lim = (NOUT - base < 64 ? NOUT - base : 64) * CP;
        for (int i = l; i < lim; i += 64)
            gself[(size_t)base * CP + i] = T[(i / CP) * 49 + (i % CP)];
    }
}

// ---------------------------------------------------------------------------
// final: out[n] = log_softmax( mean_{s in N(n)} gsrc[s] + gself[n] )
// One wave per output node; lanes own channels; 192B-row gathers.
__global__ __launch_bounds__(64) void final_kernel(const float* __restrict__ gsrc,
        const float* __restrict__ gself, const int* __restrict__ row_ptr,
        const int* __restrict__ col, float* __restrict__ out) {
    int n = blockIdx.x;
    int c = threadIdx.x;
    int b = row_ptr[n], e = row_ptr[n + 1];
    float inv = 1.0f / (float)max(e - b, 1);
    float a0 = 0.f, a1 = 0.f;
    if (c < CP) {
        int j = b;
        for (; j + 1 < e; j += 2) {
            a0 += gsrc[(size_t)col[j] * CP + c];
            a1 += gsrc[(size_t)col[j + 1] * CP + c];
        }
        if (j < e) a0 += gsrc[(size_t)col[j] * CP + c];
    }
    float val = (c < COUT) ? ((a0 + a1) * inv + gself[(size_t)n * CP + c]) : -INFINITY;
    float m = val;
    #pragma unroll
    for (int off = 32; off > 0; off >>= 1) m = fmaxf(m, __shfl_xor(m, off, 64));
    float ex = (c < COUT) ? expf(val - m) : 0.f;
    float ssum = ex;
    #pragma unroll
    for (int off = 32; off > 0; off >>= 1) ssum += __shfl_xor(ssum, off, 64);
    if (c < COUT) out[(size_t)n * COUT + c] = val - m - logf(ssum);
}

// ---------------------------------------------------------------------------
extern "C" void kernel_launch(void* const* d_in, const int* in_sizes, int n_in,
                              void* d_out, int out_size, void* d_ws, size_t ws_size,
                              hipStream_t stream) {
    const float* x   = (const float*)d_in[0];
    const int*   ei  = (const int*)d_in[1];   // [2, E]: row 0 = src, row 1 = dst
    const int*   src = ei;
    const int*   dst = ei + E;
    const float* w1l = (const float*)d_in[3];
    const float* b1l = (const float*)d_in[4];
    const float* w1r = (const float*)d_in[5];
    const float* w2l = (const float*)d_in[6];
    const float* b2l = (const float*)d_in[7];
    const float* w2r = (const float*)d_in[8];
    float* out = (float*)d_out;

    // workspace layout: ints [cnt N | row_ptr N+1 | cursor N | blkSum NB | blkOff NB | col E]
    // then floats [agg1 N*CIN (later gsrc N*CP + gself NOUT*CP)] [hT CH*N]
    int* cnt     = (int*)d_ws;
    int* row_ptr = cnt + N;
    int* cursor  = row_ptr + N + 1;
    int* blkSum  = cursor + N;
    int* blkOff  = blkSum + NB;
    int* col     = blkOff + NB;
    size_t intWords = (size_t)N + (N + 1) + N + NB + NB + E;
    intWords = (intWords + 3) & ~(size_t)3;
    float* agg1  = (float*)d_ws + intWords;
    float* hT    = agg1 + (size_t)N * CIN;
    float* gsrc  = agg1;                          // alias: agg1 dead after gemm1
    float* gself = gsrc + (size_t)N * CP;
    // total ws: ~49.4 MB (< 58.6 MB proven available in round 1)

    hipMemsetAsync(cnt, 0, (size_t)N * sizeof(int), stream);
    hist_kernel <<<(E + 255) / 256, 256, 0, stream>>>(dst, cnt);
    scan_blocks <<<NB, 256, 0, stream>>>(cnt, row_ptr, blkSum);
    scan_sums   <<<1, 256, 0, stream>>>(blkSum, blkOff);
    scan_add    <<<NB, 256, 0, stream>>>(row_ptr, cursor, blkOff);
    fill_kernel <<<(E + 255) / 256, 256, 0, stream>>>(src, dst, cursor, col);
    gather1_kernel<<<N / 8,        128, 0, stream>>>(x, row_ptr, col, agg1);
    gemm1_kernel  <<<(N + 63) / 64, 256, 0, stream>>>(agg1, x, w1l, b1l, w1r, hT);
    gemm2_kernel  <<<(N + 63) / 64,  64, 0, stream>>>(hT, w2l, b2l, w2r, gsrc, gself);
    final_kernel  <<<NOUT,           64, 0, stream>>>(gsrc, gself, row_ptr, col, out);
}

// Round 7
// 366.516 us; speedup vs baseline: 2.4228x; 1.0239x over previous
//
#include <hip/hip_runtime.h>
#include <math.h>

// Problem constants (from reference setup_inputs)
constexpr int N    = 50000;   // nodes
constexpr int E    = 800000;  // edges
constexpr int CIN  = 100;     // input channels
constexpr int CH   = 128;     // hidden channels
constexpr int COUT = 47;      // output channels
constexpr int NOUT = 25000;   // original_size (rows emitted)
constexpr int CP   = 48;      // COUT padded (alignment / lane mapping)
constexpr int NB   = (N + 255) / 256;   // 196 scan blocks

// ---------------------------------------------------------------------------
// CSR build stage 1: in-degree histogram (int atomics, low contention)
__global__ void hist_kernel(const int* __restrict__ dst, int* __restrict__ cnt) {
    int i = blockIdx.x * blockDim.x + threadIdx.x;
    if (i < E) atomicAdd(&cnt[dst[i]], 1);
}

// CSR build stage 2a: per-block exclusive scan of cnt (coalesced, parallel)
__global__ __launch_bounds__(256) void scan_blocks(const int* __restrict__ cnt,
        int* __restrict__ row_ptr, int* __restrict__ blkSum) {
    __shared__ int s[256];
    int t = threadIdx.x;
    int i = blockIdx.x * 256 + t;
    int v = (i < N) ? cnt[i] : 0;
    s[t] = v;
    __syncthreads();
    for (int off = 1; off < 256; off <<= 1) {
        int a = s[t];
        int u = (t >= off) ? s[t - off] : 0;
        __syncthreads();
        s[t] = a + u;
        __syncthreads();
    }
    if (i < N) row_ptr[i] = s[t] - v;          // local exclusive prefix
    if (t == 255) blkSum[blockIdx.x] = s[255]; // block total
}

// CSR build stage 2b: scan the 196 block sums (single tiny block)
__global__ __launch_bounds__(256) void scan_sums(int* __restrict__ blkSum,
        int* __restrict__ blkOff) {
    __shared__ int s[256];
    int t = threadIdx.x;
    int v = (t < NB) ? blkSum[t] : 0;
    s[t] = v;
    __syncthreads();
    for (int off = 1; off < 256; off <<= 1) {
        int a = s[t];
        int u = (t >= off) ? s[t - off] : 0;
        __syncthreads();
        s[t] = a + u;
        __syncthreads();
    }
    if (t < NB) blkOff[t] = s[t] - v;          // exclusive offsets
}

// CSR build stage 2c: apply block offsets; produce cursor copy; row_ptr[N]=E
__global__ __launch_bounds__(256) void scan_add(int* __restrict__ row_ptr,
        int* __restrict__ cursor, const int* __restrict__ blkOff) {
    int i = blockIdx.x * 256 + threadIdx.x;
    if (i < N) {
        int v = row_ptr[i] + blkOff[blockIdx.x];
        row_ptr[i] = v;
        cursor[i]  = v;
        if (i == N - 1) row_ptr[N] = E;
    }
}

// CSR build stage 3: bucket-fill edge sources (int atomics on cursors)
__global__ void fill_kernel(const int* __restrict__ src, const int* __restrict__ dst,
        int* __restrict__ cursor, int* __restrict__ col) {
    int i = blockIdx.x * blockDim.x + threadIdx.x;
    if (i < E) {
        int d = dst[i];
        int p = atomicAdd(&cursor[d], 1);
        col[p] = src[i];
    }
}

// Pad layer-2 weights to 48 columns (col 47 = 0) so the fused kernel's
// channel-split waves need no bounds logic and garbage channels are exact 0.
__global__ __launch_bounds__(256) void pad_w2(const float* __restrict__ w2l,
        const float* __restrict__ w2r, const float* __restrict__ b2l,
        float* __restrict__ w2lp, float* __restrict__ w2rp, float* __restrict__ b2p) {
    int i = blockIdx.x * 256 + threadIdx.x;
    if (i < CH * CP) {
        int k = i / CP, c = i - k * CP;
        w2lp[i] = (c < COUT) ? w2l[k * COUT + c] : 0.0f;
        w2rp[i] = (c < COUT) ? w2r[k * COUT + c] : 0.0f;
    }
    if (i < CP) b2p[i] = (i < COUT) ? b2l[i] : 0.0f;
}

// ---------------------------------------------------------------------------
// gather1: agg1[n] = mean_{s in N(n)} x[s]   (row-major [N][CIN], no atomics)
__global__ __launch_bounds__(128) void gather1_kernel(const float* __restrict__ x,
        const int* __restrict__ row_ptr, const int* __restrict__ col,
        float* __restrict__ agg1) {
    int f = threadIdx.x;
    int base = blockIdx.x * 8;
    if (f >= CIN) return;
    for (int r = 0; r < 8; ++r) {
        int n = base + r;
        int b = row_ptr[n], e = row_ptr[n + 1];
        float inv = 1.0f / (float)max(e - b, 1);
        float a0 = 0.f, a1 = 0.f, a2 = 0.f, a3 = 0.f;
        int j = b;
        for (; j + 3 < e; j += 4) {
            int s0 = col[j], s1 = col[j + 1], s2 = col[j + 2], s3 = col[j + 3];
            a0 += x[s0 * CIN + f];
            a1 += x[s1 * CIN + f];
            a2 += x[s2 * CIN + f];
            a3 += x[s3 * CIN + f];
        }
        for (; j < e; ++j) a0 += x[col[j] * CIN + f];
        agg1[n * CIN + f] = ((a0 + a1) + (a2 + a3)) * inv;
    }
}

// ---------------------------------------------------------------------------
// R7 fused gemm: per 64-node tile, compute h = mean@w1l + x@w1r + b1l into LDS,
// then gsrc = h@w2lp (all n) and gself = h@w2rp + b2p (n < NOUT) directly.
// Eliminates hT (25.6MB write + 25.6MB read) and the 6%-occupancy gemm2.
// 512 thr = 8 waves: stage1 wave w owns 16 channels; stage2 waves 0-3 -> gsrc
// (12 ch each), waves 4-7 -> gself. LDS: feat(64x101) aliased under hbuf(64x129)
// = 33KB -> 4 blocks/CU by LDS & threads (grid 782 -> ~3/CU, ~24 waves/CU).
// readfirstlane keeps weight addressing provably wave-uniform (R4 lesson).
__global__ __launch_bounds__(512) void fused_gemm_kernel(
        const float* __restrict__ agg1, const float* __restrict__ x,
        const float* __restrict__ w1l, const float* __restrict__ b1l,
        const float* __restrict__ w1r,
        const float* __restrict__ w2lp, const float* __restrict__ b2p,
        const float* __restrict__ w2rp,
        float* __restrict__ gsrc, float* __restrict__ gself) {
    __shared__ float buf[64 * 129];   // feat stride 101 (stages A/B), hbuf stride 129
    int t = threadIdx.x;
    int base = blockIdx.x * 64;
    int r = t & 63;
    int wv = t >> 6;                  // 0..7
    int c0 = __builtin_amdgcn_readfirstlane(wv * 16);
    int limit = (N - base < 64 ? N - base : 64) * CIN;
    float acc[16];
    #pragma unroll
    for (int c = 0; c < 16; ++c) acc[c] = b1l[c0 + c];

    // stage 1, phase A: mean rows
    for (int i = t; i < 64 * CIN; i += 512)
        buf[(i / CIN) * 101 + (i % CIN)] =
            (i < limit) ? agg1[(size_t)base * CIN + i] : 0.0f;
    __syncthreads();
    const float* frow = buf + r * 101;
    for (int k = 0; k < CIN; ++k) {
        float fv = frow[k];
        const float* w = w1l + k * CH + c0;   // uniform -> s_load
        #pragma unroll
        for (int c = 0; c < 16; ++c) acc[c] = fmaf(fv, w[c], acc[c]);
    }
    __syncthreads();
    // stage 1, phase B: self rows
    for (int i = t; i < 64 * CIN; i += 512)
        buf[(i / CIN) * 101 + (i % CIN)] =
            (i < limit) ? x[(size_t)base * CIN + i] : 0.0f;
    __syncthreads();
    for (int k = 0; k < CIN; ++k) {
        float fv = frow[k];
        const float* w = w1r + k * CH + c0;
        #pragma unroll
        for (int c = 0; c < 16; ++c) acc[c] = fmaf(fv, w[c], acc[c]);
    }
    __syncthreads();                  // feat dead -> reuse as hbuf
    #pragma unroll
    for (int c = 0; c < 16; ++c)
        buf[r * 129 + c0 + c] = acc[c];   // (r + c0 + c) % 32: 2-way, free
    __syncthreads();                  // last barrier

    // stage 2: channel-split h @ w2 from LDS
    bool isSelf = (wv >= 4);
    if (isSelf && base >= NOUT) return;   // safe: no barriers below
    int d0 = __builtin_amdgcn_readfirstlane((wv & 3) * 12);
    const float* W = isSelf ? w2rp : w2lp;
    const float* hrow = buf + r * 129;
    float a2[12];
    #pragma unroll
    for (int c = 0; c < 12; ++c) a2[c] = isSelf ? b2p[d0 + c] : 0.0f;
    for (int k = 0; k < CH; ++k) {
        float fv = hrow[k];
        const float* w = W + k * CP + d0;   // uniform 48B row slice -> s_load
        #pragma unroll
        for (int c = 0; c < 12; ++c) a2[c] = fmaf(fv, w[c], a2[c]);
    }
    int n = base + r;
    if (isSelf) {
        if (n < NOUT) {
            #pragma unroll
            for (int c = 0; c < 12; ++c) gself[(size_t)n * CP + d0 + c] = a2[c];
        }
    } else {
        if (n < N) {
            #pragma unroll
            for (int c = 0; c < 12; ++c) gsrc[(size_t)n * CP + d0 + c] = a2[c];
        }
    }
}

// ---------------------------------------------------------------------------
// final: out[n] = log_softmax( mean_{s in N(n)} gsrc[s] + gself[n] )
// One wave per output node; lanes own channels; 192B-row gathers.
__global__ __launch_bounds__(64) void final_kernel(const float* __restrict__ gsrc,
        const float* __restrict__ gself, const int* __restrict__ row_ptr,
        const int* __restrict__ col, float* __restrict__ out) {
    int n = blockIdx.x;
    int c = threadIdx.x;
    int b = row_ptr[n], e = row_ptr[n + 1];
    float inv = 1.0f / (float)max(e - b, 1);
    float a0 = 0.f, a1 = 0.f;
    if (c < CP) {
        int j = b;
        for (; j + 1 < e; j += 2) {
            a0 += gsrc[(size_t)col[j] * CP + c];
            a1 += gsrc[(size_t)col[j + 1] * CP + c];
        }
        if (j < e) a0 += gsrc[(size_t)col[j] * CP + c];
    }
    float val = (c < COUT) ? ((a0 + a1) * inv + gself[(size_t)n * CP + c]) : -INFINITY;
    float m = val;
    #pragma unroll
    for (int off = 32; off > 0; off >>= 1) m = fmaxf(m, __shfl_xor(m, off, 64));
    float ex = (c < COUT) ? expf(val - m) : 0.f;
    float ssum = ex;
    #pragma unroll
    for (int off = 32; off > 0; off >>= 1) ssum += __shfl_xor(ssum, off, 64);
    if (c < COUT) out[(size_t)n * COUT + c] = val - m - logf(ssum);
}

// ---------------------------------------------------------------------------
extern "C" void kernel_launch(void* const* d_in, const int* in_sizes, int n_in,
                              void* d_out, int out_size, void* d_ws, size_t ws_size,
                              hipStream_t stream) {
    const float* x   = (const float*)d_in[0];
    const int*   ei  = (const int*)d_in[1];   // [2, E]: row 0 = src, row 1 = dst
    const int*   src = ei;
    const int*   dst = ei + E;
    const float* w1l = (const float*)d_in[3];
    const float* b1l = (const float*)d_in[4];
    const float* w1r = (const float*)d_in[5];
    const float* w2l = (const float*)d_in[6];
    const float* b2l = (const float*)d_in[7];
    const float* w2r = (const float*)d_in[8];
    float* out = (float*)d_out;

    // workspace: ints [cnt N | row_ptr N+1 | cursor N | blkSum NB | blkOff NB | col E]
    // floats [agg1 N*CIN | gsrc N*CP | gself NOUT*CP | w2lp CH*CP | w2rp CH*CP | b2p CP]
    // (agg1 may NOT alias gsrc anymore: fused kernel reads agg1 while writing gsrc)
    int* cnt     = (int*)d_ws;
    int* row_ptr = cnt + N;
    int* cursor  = row_ptr + N + 1;
    int* blkSum  = cursor + N;
    int* blkOff  = blkSum + NB;
    int* col     = blkOff + NB;
    size_t intWords = (size_t)N + (N + 1) + N + NB + NB + E;
    intWords = (intWords + 3) & ~(size_t)3;
    float* agg1  = (float*)d_ws + intWords;
    float* gsrc  = agg1 + (size_t)N * CIN;
    float* gself = gsrc + (size_t)N * CP;
    float* w2lp  = gself + (size_t)NOUT * CP;
    float* w2rp  = w2lp + CH * CP;
    float* b2p   = w2rp + CH * CP;
    // total ws ~38.4 MB (< 58.6 MB proven available)

    hipMemsetAsync(cnt, 0, (size_t)N * sizeof(int), stream);
    pad_w2      <<<(CH * CP + 255) / 256, 256, 0, stream>>>(w2l, w2r, b2l, w2lp, w2rp, b2p);
    hist_kernel <<<(E + 255) / 256, 256, 0, stream>>>(dst, cnt);
    scan_blocks <<<NB, 256, 0, stream>>>(cnt, row_ptr, blkSum);
    scan_sums   <<<1, 256, 0, stream>>>(blkSum, blkOff);
    scan_add    <<<NB, 256, 0, stream>>>(row_ptr, cursor, blkOff);
    fill_kernel <<<(E + 255) / 256, 256, 0, stream>>>(src, dst, cursor, col);
    gather1_kernel  <<<N / 8, 128, 0, stream>>>(x, row_ptr, col, agg1);
    fused_gemm_kernel<<<(N + 63) / 64, 512, 0, stream>>>(agg1, x, w1l, b1l, w1r,
                                                         w2lp, b2p, w2rp, gsrc, gself);
    final_kernel    <<<NOUT, 64, 0, stream>>>(gsrc, gself, row_ptr, col, out);
}